// Round 9
// baseline (2276.337 us; speedup 1.0000x reference)
//
#include <hip/hip_runtime.h>

#define SEQ    256
#define BATCHN 2048
#define NIN    64
#define H      128
#define NOUT   64
#define TOUT   128
#define BT     16     // batch rows per block -> 128 blocks
#define ASTR   200    // LDS A-row stride in halfs (192 + 8 pad)
#define TCH    16     // decoder steps buffered before a coalesced flush
#define WSTR   136    // W'-prep LDS row stride in halfs (128 + 8; 272B = 17*16 keeps b128 alignment)
#define LOG2E  1.44269504f

using half8 = _Float16 __attribute__((ext_vector_type(8)));
using f32x4 = float    __attribute__((ext_vector_type(4)));

__device__ __forceinline__ float ex2(float v) { return __builtin_amdgcn_exp2f(v); }

__device__ __forceinline__ half8 ldfrag8(const float* __restrict__ p, float s) {
    half8 r;
#pragma unroll
    for (int e = 0; e < 8; ++e) r[e] = (_Float16)(p[e] * s);
    return r;
}

// Fused seq2seq, round 9.
// Encoder: round-5 skeleton (1 barrier/step, x prefetched one FULL step ahead) with
// exp2-direct activations (weights pre-scaled by log2e / 2*log2e).
// Decoder: algebraically fused recurrence  gates_k = W'.h_{k-1} + b'  where
//   W' = dWih @ oW + dWhh,  b' = db + dWih @ ob   (y eliminated from the chain;
// y_k = oW.h_k + ob computed off-path by waves 0-3 for output staging only).
// MFMA 16x16x32 f16 maps (HW-verified r2-r3): A row = lane&15, B col = lane&15,
// D row = 4*(lane>>4)+r, D col = lane&15.
__global__ __launch_bounds__(512, 2) void seq2seq_fused(
    const float* __restrict__ x,
    const float* __restrict__ eWih, const float* __restrict__ eWhh, const float* __restrict__ eb,
    const float* __restrict__ dWih, const float* __restrict__ dWhh, const float* __restrict__ db,
    const float* __restrict__ oW,   const float* __restrict__ obv,
    float* __restrict__ out)
{
    __shared__ __align__(16) _Float16 als[2][BT][ASTR];  // [b][k], k: 0..63 = x, 64..191 = h
    __shared__ __align__(16) _Float16 ybuf[TCH][BT][68]; // decoder y staging; ALIASED as W'-prep scratch

    const int tid  = threadIdx.x;
    const int lane = tid & 63;
    const int w    = tid >> 6;
    const int jl   = lane & 15;
    const int lg   = lane >> 4;
    const int b0   = blockIdx.x * BT;

    float c[4] = {0.f, 0.f, 0.f, 0.f};   // cell state, rows 4*lg+r, col 16w+jl

    // ---------------- encoder weights -> resident VGPR fragments (pre-scaled) ----------------
    half8 wf[4][6];
    float bq[4];
#pragma unroll
    for (int q = 0; q < 4; ++q) {
        const float sq = (q == 2) ? 2.f * LOG2E : LOG2E;
        const int j = q * H + w * 16 + jl;
#pragma unroll
        for (int kc = 0; kc < 2; ++kc)
            wf[q][kc] = ldfrag8(eWih + j * NIN + kc * 32 + lg * 8, sq);
#pragma unroll
        for (int kc = 2; kc < 6; ++kc)
            wf[q][kc] = ldfrag8(eWhh + j * H + (kc - 2) * 32 + lg * 8, sq);
        bq[q] = eb[j] * sq;
    }

    for (int i = tid; i < 2 * BT * ASTR; i += 512) ((_Float16*)als)[i] = (_Float16)0.f;
    __syncthreads();
    const int xi = tid >> 5, xn = (tid & 31) * 2;
    {
        const float2 xv = *(const float2*)(x + (b0 + xi) * NIN + xn);
        als[0][xi][xn]     = (_Float16)xv.x;
        als[0][xi][xn + 1] = (_Float16)xv.y;
    }
    __syncthreads();

    // activation phases (ILP across r): 5 exp2 + 3 rcp per (row,col); writes h -> als[nxt]
    auto act_store = [&](const f32x4 ac[4], int nxt) {
        float A0[4], B0[4], F0[4], D0[4], E2[4], itv[4], hv[4];
#pragma unroll
        for (int r = 0; r < 4; ++r) A0[r] = ex2(-ac[0][r]);
#pragma unroll
        for (int r = 0; r < 4; ++r) B0[r] = ex2(fminf(ac[2][r], 44.f));
#pragma unroll
        for (int r = 0; r < 4; ++r) F0[r] = ex2(-ac[1][r]);
#pragma unroll
        for (int r = 0; r < 4; ++r) D0[r] = ex2(-ac[3][r]);
#pragma unroll
        for (int r = 0; r < 4; ++r)
            itv[r] = (B0[r] - 1.f) * __builtin_amdgcn_rcpf((1.f + A0[r]) * (1.f + B0[r]));
#pragma unroll
        for (int r = 0; r < 4; ++r)
            c[r] = __builtin_amdgcn_rcpf(1.f + F0[r]) * c[r] + itv[r];
#pragma unroll
        for (int r = 0; r < 4; ++r) E2[r] = ex2(fminf(2.8853901f * c[r], 44.f));
#pragma unroll
        for (int r = 0; r < 4; ++r)
            hv[r] = (E2[r] - 1.f) * __builtin_amdgcn_rcpf((1.f + D0[r]) * (1.f + E2[r]));
#pragma unroll
        for (int r = 0; r < 4; ++r)
            als[nxt][lg * 4 + r][NIN + w * 16 + jl] = (_Float16)hv[r];
    };

    // ---------------- encoder: 256 steps, 1 barrier/step, x one full step ahead ----------------
    for (int t = 0; t < SEQ; ++t) {
        const int cur = t & 1, nxt = cur ^ 1;

        float2 xv = make_float2(0.f, 0.f);
        if (t + 1 < SEQ)
            xv = *(const float2*)(x + ((size_t)(t + 1) * BATCHN + b0 + xi) * NIN + xn);

        half8 af[6];
#pragma unroll
        for (int kc = 0; kc < 6; ++kc)
            af[kc] = *(const half8*)&als[cur][jl][kc * 32 + lg * 8];

        f32x4 ac[4];
#pragma unroll
        for (int q = 0; q < 4; ++q) {
            f32x4 aA = {bq[q], bq[q], bq[q], bq[q]};
            f32x4 aB = {0.f, 0.f, 0.f, 0.f};
#pragma unroll
            for (int kc = 0; kc < 3; ++kc) {
                aA = __builtin_amdgcn_mfma_f32_16x16x32_f16(af[kc],     wf[q][kc],     aA, 0, 0, 0);
                aB = __builtin_amdgcn_mfma_f32_16x16x32_f16(af[kc + 3], wf[q][kc + 3], aB, 0, 0, 0);
            }
            ac[q] = aA + aB;
        }

        act_store(ac, nxt);
        als[nxt][xi][xn]     = (_Float16)xv.x;
        als[nxt][xi][xn + 1] = (_Float16)xv.y;
        __syncthreads();
    }
    // h_enc now in als[0]

    // ---------------- decoder setup ----------------
    half8 of[4];
    float oB = 0.f;
    if (w < 4) {  // waves 0..3 own the y-GEMM (natural units)
        const int j = w * 16 + jl;
#pragma unroll
        for (int kc = 0; kc < 4; ++kc)
            of[kc] = ldfrag8(oW + j * H + kc * 32 + lg * 8, 1.f);
        oB = obv[j];
    }

    // step k=0: gates = dWhh . h_enc + db  (x0 = 0)
#pragma unroll
    for (int q = 0; q < 4; ++q) {
        const float sq = (q == 2) ? 2.f * LOG2E : LOG2E;
        const int j = q * H + w * 16 + jl;
#pragma unroll
        for (int kc = 0; kc < 4; ++kc)
            wf[q][kc] = ldfrag8(dWhh + j * H + kc * 32 + lg * 8, sq);
        bq[q] = db[j] * sq;
    }
    {
        half8 af[4];
#pragma unroll
        for (int kc = 0; kc < 4; ++kc)
            af[kc] = *(const half8*)&als[0][jl][NIN + kc * 32 + lg * 8];
        f32x4 ac[4];
#pragma unroll
        for (int q = 0; q < 4; ++q) {
            f32x4 aA = {bq[q], bq[q], bq[q], bq[q]};
            f32x4 aB = {0.f, 0.f, 0.f, 0.f};
            aA = __builtin_amdgcn_mfma_f32_16x16x32_f16(af[0], wf[q][0], aA, 0, 0, 0);
            aB = __builtin_amdgcn_mfma_f32_16x16x32_f16(af[1], wf[q][1], aB, 0, 0, 0);
            aA = __builtin_amdgcn_mfma_f32_16x16x32_f16(af[2], wf[q][2], aA, 0, 0, 0);
            aB = __builtin_amdgcn_mfma_f32_16x16x32_f16(af[3], wf[q][3], aB, 0, 0, 0);
            ac[q] = aA + aB;
        }
        act_store(ac, 1);   // h_0 -> als[1]
        __syncthreads();
    }

    // ---------------- W' prep: wf := frags of (dWih@oW + dWhh)*sq ; bq := (db + dWih@ob)*sq ----
    // Scratch aliases ybuf (ybuf's first real write happens after prep). Per-wave region [16][WSTR].
    {
        _Float16* mybuf = ((_Float16*)ybuf) + (size_t)w * 16 * WSTR;
#pragma unroll 1
        for (int q = 0; q < 4; ++q) {
            const float sq = (q == 2) ? 2.f * LOG2E : LOG2E;
            const int jb = q * H + w * 16;           // wave's 16-row j-tile base
            half8 afp[2];
#pragma unroll
            for (int k2 = 0; k2 < 2; ++k2)
                afp[k2] = ldfrag8(dWih + (jb + jl) * NIN + k2 * 32 + lg * 8, 1.f);
#pragma unroll 1
            for (int nt = 0; nt < 8; ++nt) {
                half8 bf0, bf1;                      // oW[m][nt*16+jl], m = k2*32 + lg*8 + e
#pragma unroll
                for (int e = 0; e < 8; ++e) {
                    bf0[e] = (_Float16)oW[(lg * 8 + e) * H + nt * 16 + jl];
                    bf1[e] = (_Float16)oW[(32 + lg * 8 + e) * H + nt * 16 + jl];
                }
                f32x4 acc;
#pragma unroll
                for (int r = 0; r < 4; ++r)
                    acc[r] = dWhh[(jb + lg * 4 + r) * H + nt * 16 + jl];
                acc = __builtin_amdgcn_mfma_f32_16x16x32_f16(afp[0], bf0, acc, 0, 0, 0);
                acc = __builtin_amdgcn_mfma_f32_16x16x32_f16(afp[1], bf1, acc, 0, 0, 0);
#pragma unroll
                for (int r = 0; r < 4; ++r)
                    mybuf[(lg * 4 + r) * WSTR + nt * 16 + jl] = (_Float16)(acc[r] * sq);
            }
            __syncthreads();                          // wbuf(q) complete
#pragma unroll
            for (int kc = 0; kc < 4; ++kc)
                wf[q][kc] = *(const half8*)&mybuf[jl * WSTR + kc * 32 + lg * 8];
            float s = db[jb + jl];
            for (int m = 0; m < NIN; ++m) s += dWih[(jb + jl) * NIN + m] * obv[m];
            bq[q] = s * sq;
            __syncthreads();                          // frags read before next q overwrites
        }
    }

    // ---------------- decoder steady loop: i = 1..128, 1 barrier/step ----------------
    // Iter i: reads h_{i-1} from als[i&1]; computes y_{i-1} (waves 0-3, off-path) and,
    // for i<128, gates_i via W' -> h_i -> als[(i&1)^1].
    for (int i = 1; i <= TOUT; ++i) {
        const int cur = i & 1, nxt = cur ^ 1;

        half8 af[4];
#pragma unroll
        for (int kc = 0; kc < 4; ++kc)
            af[kc] = *(const half8*)&als[cur][jl][NIN + kc * 32 + lg * 8];

        if (w < 4) {   // y_{i-1} = oW . h_{i-1} + ob  (output only; not in the chain)
            f32x4 ya = {oB, oB, oB, oB};
#pragma unroll
            for (int kc = 0; kc < 4; ++kc)
                ya = __builtin_amdgcn_mfma_f32_16x16x32_f16(af[kc], of[kc], ya, 0, 0, 0);
            const int tt = (i - 1) & (TCH - 1);
            const int j = w * 16 + jl;
#pragma unroll
            for (int r = 0; r < 4; ++r)
                ybuf[tt][lg * 4 + r][j] = (_Float16)ya[r];
        }

        if (i < TOUT) {
            f32x4 ac[4];
#pragma unroll
            for (int q = 0; q < 4; ++q) {
                f32x4 aA = {bq[q], bq[q], bq[q], bq[q]};
                f32x4 aB = {0.f, 0.f, 0.f, 0.f};
                aA = __builtin_amdgcn_mfma_f32_16x16x32_f16(af[0], wf[q][0], aA, 0, 0, 0);
                aB = __builtin_amdgcn_mfma_f32_16x16x32_f16(af[1], wf[q][1], aB, 0, 0, 0);
                aA = __builtin_amdgcn_mfma_f32_16x16x32_f16(af[2], wf[q][2], aA, 0, 0, 0);
                aB = __builtin_amdgcn_mfma_f32_16x16x32_f16(af[3], wf[q][3], aB, 0, 0, 0);
                ac[q] = aA + aB;
            }
            act_store(ac, nxt);
        }
        __syncthreads();   // h_i + ybuf visible

        if ((i & (TCH - 1)) == 0) {   // i = 16,32,...,128: flush y[i-16 .. i-1]
            const int t0 = i - TCH;
#pragma unroll
            for (int it = 0; it < 8; ++it) {
                const int slot = it * 512 + tid;   // 0..4095
                const int pair = slot >> 2;        // (row,j): 0..1023
                const int tq   = slot & 3;
                const int row  = pair >> 6;
                const int j    = pair & 63;
                float4 v;
                v.x = (float)ybuf[tq * 4 + 0][row][j];
                v.y = (float)ybuf[tq * 4 + 1][row][j];
                v.z = (float)ybuf[tq * 4 + 2][row][j];
                v.w = (float)ybuf[tq * 4 + 3][row][j];
                *(float4*)(out + ((size_t)(b0 + row) * NOUT + j) * TOUT + t0 + tq * 4) = v;
            }
            __syncthreads();   // flush done before next iter's ybuf writes (WAR)
        }
    }
}

extern "C" void kernel_launch(void* const* d_in, const int* in_sizes, int n_in,
                              void* d_out, int out_size, void* d_ws, size_t ws_size,
                              hipStream_t stream) {
    (void)in_sizes; (void)n_in; (void)out_size; (void)d_ws; (void)ws_size;
    const float* x    = (const float*)d_in[0];
    const float* eWih = (const float*)d_in[1];
    const float* eWhh = (const float*)d_in[2];
    const float* eb   = (const float*)d_in[3];
    const float* dWih = (const float*)d_in[4];
    const float* dWhh = (const float*)d_in[5];
    const float* db   = (const float*)d_in[6];
    const float* oW   = (const float*)d_in[7];
    const float* ob   = (const float*)d_in[8];

    seq2seq_fused<<<BATCHN / BT, 512, 0, stream>>>(
        x, eWih, eWhh, eb, dWih, dWhh, db, oW, ob, (float*)d_out);
}

// Round 10
// 439.752 us; speedup vs baseline: 5.1764x; 5.1764x over previous
//
#include <hip/hip_runtime.h>

#define SEQ    256
#define BATCHN 2048
#define NIN    64
#define H      128
#define NOUT   64
#define TOUT   128
#define BT     16     // batch rows per block -> 128 blocks
#define ASTR   200    // LDS A-row stride in halfs (192 + 8 pad)
#define TCH    16     // decoder steps buffered before a coalesced flush
#define WSTR   136    // W'-prep LDS row stride in halfs (128 + 8; keeps 16B alignment)
#define LOG2E  1.44269504f

using half8 = _Float16 __attribute__((ext_vector_type(8)));
using f32x4 = float    __attribute__((ext_vector_type(4)));

__device__ __forceinline__ float ex2(float v) { return __builtin_amdgcn_exp2f(v); }

__device__ __forceinline__ half8 ldfrag8(const float* __restrict__ p, float s) {
    half8 r;
#pragma unroll
    for (int e = 0; e < 8; ++e) r[e] = (_Float16)(p[e] * s);
    return r;
}

// Fused seq2seq, round 10 = round 9 with the W'-prep q-loop FULLY UNROLLED so the
// wf[][] fragment array stays register-resident (r9's "#pragma unroll 1" forced
// runtime indexing -> wf spilled to scratch -> 5x regression, VGPR 124->68).
// Encoder: 1 barrier/step, x prefetched one full step ahead, exp2-direct gates.
// Decoder: gates_k = W'.h_{k-1} + b',  W' = dWih@oW + dWhh,  b' = db + dWih@ob;
// y_k = oW.h_k + ob computed off the recurrence path (waves 0-3) for staging only.
__global__ __launch_bounds__(512, 2) void seq2seq_fused(
    const float* __restrict__ x,
    const float* __restrict__ eWih, const float* __restrict__ eWhh, const float* __restrict__ eb,
    const float* __restrict__ dWih, const float* __restrict__ dWhh, const float* __restrict__ db,
    const float* __restrict__ oW,   const float* __restrict__ obv,
    float* __restrict__ out)
{
    __shared__ __align__(16) _Float16 als[2][BT][ASTR];  // [b][k], k: 0..63 = x, 64..191 = h
    __shared__ __align__(16) _Float16 ybuf[TCH][BT][68]; // decoder y staging; ALIASED as W'-prep scratch

    const int tid  = threadIdx.x;
    const int lane = tid & 63;
    const int w    = tid >> 6;
    const int jl   = lane & 15;
    const int lg   = lane >> 4;
    const int b0   = blockIdx.x * BT;

    float c[4] = {0.f, 0.f, 0.f, 0.f};   // cell state, rows 4*lg+r, col 16w+jl

    // ---------------- encoder weights -> resident VGPR fragments (pre-scaled) ----------------
    half8 wf[4][6];
    float bq[4];
#pragma unroll
    for (int q = 0; q < 4; ++q) {
        const float sq = (q == 2) ? 2.f * LOG2E : LOG2E;
        const int j = q * H + w * 16 + jl;
#pragma unroll
        for (int kc = 0; kc < 2; ++kc)
            wf[q][kc] = ldfrag8(eWih + j * NIN + kc * 32 + lg * 8, sq);
#pragma unroll
        for (int kc = 2; kc < 6; ++kc)
            wf[q][kc] = ldfrag8(eWhh + j * H + (kc - 2) * 32 + lg * 8, sq);
        bq[q] = eb[j] * sq;
    }

    for (int i = tid; i < 2 * BT * ASTR; i += 512) ((_Float16*)als)[i] = (_Float16)0.f;
    __syncthreads();
    const int xi = tid >> 5, xn = (tid & 31) * 2;
    {
        const float2 xv = *(const float2*)(x + (b0 + xi) * NIN + xn);
        als[0][xi][xn]     = (_Float16)xv.x;
        als[0][xi][xn + 1] = (_Float16)xv.y;
    }
    __syncthreads();

    // activation phases (ILP across r): 5 exp2 + 3 rcp per (row,col); writes h -> als[nxt]
    auto act_store = [&](const f32x4 ac[4], int nxt) {
        float A0[4], B0[4], F0[4], D0[4], E2[4], itv[4], hv[4];
#pragma unroll
        for (int r = 0; r < 4; ++r) A0[r] = ex2(-ac[0][r]);
#pragma unroll
        for (int r = 0; r < 4; ++r) B0[r] = ex2(fminf(ac[2][r], 44.f));
#pragma unroll
        for (int r = 0; r < 4; ++r) F0[r] = ex2(-ac[1][r]);
#pragma unroll
        for (int r = 0; r < 4; ++r) D0[r] = ex2(-ac[3][r]);
#pragma unroll
        for (int r = 0; r < 4; ++r)
            itv[r] = (B0[r] - 1.f) * __builtin_amdgcn_rcpf((1.f + A0[r]) * (1.f + B0[r]));
#pragma unroll
        for (int r = 0; r < 4; ++r)
            c[r] = __builtin_amdgcn_rcpf(1.f + F0[r]) * c[r] + itv[r];
#pragma unroll
        for (int r = 0; r < 4; ++r) E2[r] = ex2(fminf(2.8853901f * c[r], 44.f));
#pragma unroll
        for (int r = 0; r < 4; ++r)
            hv[r] = (E2[r] - 1.f) * __builtin_amdgcn_rcpf((1.f + D0[r]) * (1.f + E2[r]));
#pragma unroll
        for (int r = 0; r < 4; ++r)
            als[nxt][lg * 4 + r][NIN + w * 16 + jl] = (_Float16)hv[r];
    };

    // ---------------- encoder: 256 steps, 1 barrier/step, x one full step ahead ----------------
    for (int t = 0; t < SEQ; ++t) {
        const int cur = t & 1, nxt = cur ^ 1;

        float2 xv = make_float2(0.f, 0.f);
        if (t + 1 < SEQ)
            xv = *(const float2*)(x + ((size_t)(t + 1) * BATCHN + b0 + xi) * NIN + xn);

        half8 af[6];
#pragma unroll
        for (int kc = 0; kc < 6; ++kc)
            af[kc] = *(const half8*)&als[cur][jl][kc * 32 + lg * 8];

        f32x4 ac[4];
#pragma unroll
        for (int q = 0; q < 4; ++q) {
            f32x4 aA = {bq[q], bq[q], bq[q], bq[q]};
            f32x4 aB = {0.f, 0.f, 0.f, 0.f};
#pragma unroll
            for (int kc = 0; kc < 3; ++kc) {
                aA = __builtin_amdgcn_mfma_f32_16x16x32_f16(af[kc],     wf[q][kc],     aA, 0, 0, 0);
                aB = __builtin_amdgcn_mfma_f32_16x16x32_f16(af[kc + 3], wf[q][kc + 3], aB, 0, 0, 0);
            }
            ac[q] = aA + aB;
        }

        act_store(ac, nxt);
        als[nxt][xi][xn]     = (_Float16)xv.x;
        als[nxt][xi][xn + 1] = (_Float16)xv.y;
        __syncthreads();
    }
    // h_enc now in als[0]

    // ---------------- decoder setup ----------------
    half8 of[4];
    float oB = 0.f;
    if (w < 4) {  // waves 0..3 own the y-GEMM (natural units)
        const int j = w * 16 + jl;
#pragma unroll
        for (int kc = 0; kc < 4; ++kc)
            of[kc] = ldfrag8(oW + j * H + kc * 32 + lg * 8, 1.f);
        oB = obv[j];
    }

    // step k=0: gates = dWhh . h_enc + db  (x0 = 0)
#pragma unroll
    for (int q = 0; q < 4; ++q) {
        const float sq = (q == 2) ? 2.f * LOG2E : LOG2E;
        const int j = q * H + w * 16 + jl;
#pragma unroll
        for (int kc = 0; kc < 4; ++kc)
            wf[q][kc] = ldfrag8(dWhh + j * H + kc * 32 + lg * 8, sq);
        bq[q] = db[j] * sq;
    }
    {
        half8 af[4];
#pragma unroll
        for (int kc = 0; kc < 4; ++kc)
            af[kc] = *(const half8*)&als[0][jl][NIN + kc * 32 + lg * 8];
        f32x4 ac[4];
#pragma unroll
        for (int q = 0; q < 4; ++q) {
            f32x4 aA = {bq[q], bq[q], bq[q], bq[q]};
            f32x4 aB = {0.f, 0.f, 0.f, 0.f};
            aA = __builtin_amdgcn_mfma_f32_16x16x32_f16(af[0], wf[q][0], aA, 0, 0, 0);
            aB = __builtin_amdgcn_mfma_f32_16x16x32_f16(af[1], wf[q][1], aB, 0, 0, 0);
            aA = __builtin_amdgcn_mfma_f32_16x16x32_f16(af[2], wf[q][2], aA, 0, 0, 0);
            aB = __builtin_amdgcn_mfma_f32_16x16x32_f16(af[3], wf[q][3], aB, 0, 0, 0);
            ac[q] = aA + aB;
        }
        act_store(ac, 1);   // h_0 -> als[1]
        __syncthreads();
    }

    // ---------------- W' prep: wf := frags of (dWih@oW + dWhh)*sq ; bq := (db + dWih@ob)*sq ----
    // q-loop FULLY UNROLLED (compile-time q) so wf[][] stays in registers.
    {
        _Float16* mybuf = ((_Float16*)ybuf) + (size_t)w * 16 * WSTR;
#pragma unroll
        for (int q = 0; q < 4; ++q) {
            const float sq = (q == 2) ? 2.f * LOG2E : LOG2E;
            const int jb = q * H + w * 16;           // wave's 16-row j-tile base
            half8 afp[2];
#pragma unroll
            for (int k2 = 0; k2 < 2; ++k2)
                afp[k2] = ldfrag8(dWih + (jb + jl) * NIN + k2 * 32 + lg * 8, 1.f);
#pragma unroll 1
            for (int nt = 0; nt < 8; ++nt) {
                half8 bf0, bf1;                      // oW[m][nt*16+jl], m = k2*32 + lg*8 + e
#pragma unroll
                for (int e = 0; e < 8; ++e) {
                    bf0[e] = (_Float16)oW[(lg * 8 + e) * H + nt * 16 + jl];
                    bf1[e] = (_Float16)oW[(32 + lg * 8 + e) * H + nt * 16 + jl];
                }
                f32x4 acc;
#pragma unroll
                for (int r = 0; r < 4; ++r)
                    acc[r] = dWhh[(jb + lg * 4 + r) * H + nt * 16 + jl];
                acc = __builtin_amdgcn_mfma_f32_16x16x32_f16(afp[0], bf0, acc, 0, 0, 0);
                acc = __builtin_amdgcn_mfma_f32_16x16x32_f16(afp[1], bf1, acc, 0, 0, 0);
#pragma unroll
                for (int r = 0; r < 4; ++r)
                    mybuf[(lg * 4 + r) * WSTR + nt * 16 + jl] = (_Float16)(acc[r] * sq);
            }
            __syncthreads();                          // wave's W'(q) tile complete in LDS
#pragma unroll
            for (int kc = 0; kc < 4; ++kc)
                wf[q][kc] = *(const half8*)&mybuf[jl * WSTR + kc * 32 + lg * 8];
            float s = db[jb + jl];
            for (int m = 0; m < NIN; ++m) s += dWih[(jb + jl) * NIN + m] * obv[m];
            bq[q] = s * sq;
            __syncthreads();                          // frags read before next q overwrites
        }
    }

    // ---------------- decoder steady loop: i = 1..128, 1 barrier/step ----------------
    // Iter i: reads h_{i-1} from als[i&1]; computes y_{i-1} (waves 0-3, off-path) and,
    // for i<128, gates_i via W' -> h_i -> als[(i&1)^1].
    for (int i = 1; i <= TOUT; ++i) {
        const int cur = i & 1, nxt = cur ^ 1;

        half8 af[4];
#pragma unroll
        for (int kc = 0; kc < 4; ++kc)
            af[kc] = *(const half8*)&als[cur][jl][NIN + kc * 32 + lg * 8];

        if (w < 4) {   // y_{i-1} = oW . h_{i-1} + ob  (output only; not in the chain)
            f32x4 ya = {oB, oB, oB, oB};
#pragma unroll
            for (int kc = 0; kc < 4; ++kc)
                ya = __builtin_amdgcn_mfma_f32_16x16x32_f16(af[kc], of[kc], ya, 0, 0, 0);
            const int tt = (i - 1) & (TCH - 1);
            const int j = w * 16 + jl;
#pragma unroll
            for (int r = 0; r < 4; ++r)
                ybuf[tt][lg * 4 + r][j] = (_Float16)ya[r];
        }

        if (i < TOUT) {
            f32x4 ac[4];
#pragma unroll
            for (int q = 0; q < 4; ++q) {
                f32x4 aA = {bq[q], bq[q], bq[q], bq[q]};
                f32x4 aB = {0.f, 0.f, 0.f, 0.f};
                aA = __builtin_amdgcn_mfma_f32_16x16x32_f16(af[0], wf[q][0], aA, 0, 0, 0);
                aB = __builtin_amdgcn_mfma_f32_16x16x32_f16(af[1], wf[q][1], aB, 0, 0, 0);
                aA = __builtin_amdgcn_mfma_f32_16x16x32_f16(af[2], wf[q][2], aA, 0, 0, 0);
                aB = __builtin_amdgcn_mfma_f32_16x16x32_f16(af[3], wf[q][3], aB, 0, 0, 0);
                ac[q] = aA + aB;
            }
            act_store(ac, nxt);
        }
        __syncthreads();   // h_i + ybuf visible

        if ((i & (TCH - 1)) == 0) {   // i = 16,32,...,128: flush y[i-16 .. i-1]
            const int t0 = i - TCH;
#pragma unroll
            for (int it = 0; it < 8; ++it) {
                const int slot = it * 512 + tid;   // 0..4095
                const int pair = slot >> 2;        // (row,j): 0..1023
                const int tq   = slot & 3;
                const int row  = pair >> 6;
                const int j    = pair & 63;
                float4 v;
                v.x = (float)ybuf[tq * 4 + 0][row][j];
                v.y = (float)ybuf[tq * 4 + 1][row][j];
                v.z = (float)ybuf[tq * 4 + 2][row][j];
                v.w = (float)ybuf[tq * 4 + 3][row][j];
                *(float4*)(out + ((size_t)(b0 + row) * NOUT + j) * TOUT + t0 + tq * 4) = v;
            }
            __syncthreads();   // flush done before next iter's ybuf writes (WAR)
        }
    }
}

extern "C" void kernel_launch(void* const* d_in, const int* in_sizes, int n_in,
                              void* d_out, int out_size, void* d_ws, size_t ws_size,
                              hipStream_t stream) {
    (void)in_sizes; (void)n_in; (void)out_size; (void)d_ws; (void)ws_size;
    const float* x    = (const float*)d_in[0];
    const float* eWih = (const float*)d_in[1];
    const float* eWhh = (const float*)d_in[2];
    const float* eb   = (const float*)d_in[3];
    const float* dWih = (const float*)d_in[4];
    const float* dWhh = (const float*)d_in[5];
    const float* db   = (const float*)d_in[6];
    const float* oW   = (const float*)d_in[7];
    const float* ob   = (const float*)d_in[8];

    seq2seq_fused<<<BATCHN / BT, 512, 0, stream>>>(
        x, eWih, eWhh, eb, dWih, dWhh, db, oW, ob, (float*)d_out);
}